// Round 1
// baseline (55.921 us; speedup 1.0000x reference)
//
#include <hip/hip_runtime.h>

#define BS   16
#define NGT  20
#define NA   3
#define IH   76
#define IW   76
#define NC   80
#define PLANE (IH*IW)      /* 5776 */
#define CELLS (NA*PLANE)   /* 17328 */

// ws layout (floats): cx[320] cy[320] gw[320] gh[320] | int: cell[320] cls[320] win[320]

__device__ __forceinline__ float sigmoid_clip(float x) {
    float p = 1.0f / (1.0f + expf(-x));
    return fminf(fmaxf(p, 1e-7f), 1.0f - 1e-7f);
}

__global__ void prep_kernel(const float* __restrict__ tgt, float* __restrict__ wsf,
                            float* __restrict__ out)
{
    __shared__ int s_cell[BS*NGT];
    __shared__ int s_cnt;
    int tid = threadIdx.x;            // 0..319 == b*NGT + t
    if (tid == 0) s_cnt = 0;
    int b = tid / NGT;
    int t = tid - b * NGT;

    const float* tp = tgt + (size_t)tid * 5;
    float cx = tp[0] * (float)IW;
    float cy = tp[1] * (float)IH;
    float gw = tp[2] * (float)IW;
    float gh = tp[3] * (float)IH;
    int   cls = (int)tp[4];

    int gi = min(max((int)floorf(cx), 0), IW - 1);
    int gj = min(max((int)floorf(cy), 0), IH - 1);

    const float AW[3] = {1.5f, 2.375f, 5.0f};   // ANCHORS / 8
    const float AH[3] = {2.0f, 4.5f,   3.5f};
    float best_r = -1.0f; int best = 0;
    #pragma unroll
    for (int a = 0; a < NA; ++a) {
        float inter = fminf(gw, AW[a]) * fminf(gh, AH[a]);
        float uni   = gw*gh + AW[a]*AH[a] - inter;
        float r     = inter / uni;
        if (r > best_r) { best_r = r; best = a; }   // first-max wins, like jnp.argmax
    }

    int cell = best * PLANE + gj * IW + gi;
    s_cell[tid] = cell;
    __syncthreads();

    // last-write-wins dedup: I'm the winner iff no later target in my batch hits my cell
    int win = 1;
    for (int t2 = t + 1; t2 < NGT; ++t2)
        if (s_cell[b*NGT + t2] == cell) { win = 0; break; }

    wsf[tid]        = cx;
    wsf[320 + tid]  = cy;
    wsf[640 + tid]  = gw;
    wsf[960 + tid]  = gh;
    int* wi = (int*)(wsf + 1280);
    wi[tid]       = cell;
    wi[320 + tid] = cls;
    wi[640 + tid] = win;

    if (win) atomicAdd(&s_cnt, 1);
    __syncthreads();
    if (tid == 0) {
        out[0] = 0.0f;                              // loss accumulator (re-zero every call)
        out[1] = fmaxf((float)s_cnt, 1.0f);         // num_pos
    }
}

__global__ __launch_bounds__(256) void loss_kernel(const float* __restrict__ in,
                                                   const float* __restrict__ wsf,
                                                   float* __restrict__ out)
{
    __shared__ float sg[NGT][4];
    __shared__ int   scell[NGT], scls[NGT], swin[NGT];
    __shared__ float red[256];

    int b   = blockIdx.y;
    int tid = threadIdx.x;

    if (tid < NGT) {
        int idx = b*NGT + tid;
        sg[tid][0] = wsf[idx];
        sg[tid][1] = wsf[320 + idx];
        sg[tid][2] = wsf[640 + idx];
        sg[tid][3] = wsf[960 + idx];
        const int* wi = (const int*)(wsf + 1280);
        scell[tid] = wi[idx];
        scls[tid]  = wi[320 + idx];
        swin[tid]  = wi[640 + idx];
    }
    __syncthreads();

    int cell = blockIdx.x * 256 + tid;
    float lsum = 0.0f;

    if (cell < CELLS) {
        int a   = cell / PLANE;
        int rem = cell - a * PLANE;
        int j   = rem / IW;
        int i   = rem - j * IW;

        const float* pin = in + ((size_t)b * (NA*(5+NC)) + (size_t)a * (5+NC)) * PLANE + rem;
        float x  = pin[0];
        float y  = pin[PLANE];
        float w  = pin[2*PLANE];
        float h  = pin[3*PLANE];
        float cf = pin[4*PLANE];

        float aw = (a==0) ? 1.5f : ((a==1) ? 2.375f : 5.0f);
        float ah = (a==0) ? 2.0f : ((a==1) ? 4.5f   : 3.5f);

        // NOTE: reference adds the ROW index to x (grid_x[j,i]=j), no sigmoid on x/y
        float pbx = (float)j + x;
        float pby = (float)i + y;
        float pbw = expf(w) * aw;
        float pbh = expf(h) * ah;

        float hw = pbw*0.5f, hh = pbh*0.5f;
        float pminx = pbx-hw, pmaxx = pbx+hw;
        float pminy = pby-hh, pmaxy = pby+hh;
        float ap = pbw * pbh;

        float amax = 0.0f;
        int tw = -1;
        #pragma unroll 4
        for (int t = 0; t < NGT; ++t) {
            float gx = sg[t][0], gy = sg[t][1], gw = sg[t][2], gh = sg[t][3];
            float ghw = gw*0.5f, ghh = gh*0.5f;
            float iw_ = fmaxf(fminf(pmaxx, gx+ghw) - fmaxf(pminx, gx-ghw), 0.0f);
            float ih_ = fmaxf(fminf(pmaxy, gy+ghh) - fmaxf(pminy, gy-ghh), 0.0f);
            float inter = iw_ * ih_;
            float uni   = ap + gw*gh - inter;
            float iou   = inter / fmaxf(uni, 1e-6f);
            amax = fmaxf(amax, iou);
            if (scell[t] == cell && swin[t]) tw = t;
        }

        float p = sigmoid_clip(cf);
        if (tw >= 0) {
            // positive cell: conf BCE target 1
            lsum = -logf(p);

            // CIoU vs winner target box
            float gx = sg[tw][0], gy = sg[tw][1], gw = sg[tw][2], gh = sg[tw][3];
            float ghw = gw*0.5f, ghh = gh*0.5f;
            float gminx = gx-ghw, gmaxx = gx+ghw;
            float gminy = gy-ghh, gmaxy = gy+ghh;
            float iw_ = fmaxf(fminf(pmaxx,gmaxx) - fmaxf(pminx,gminx), 0.0f);
            float ih_ = fmaxf(fminf(pmaxy,gmaxy) - fmaxf(pminy,gminy), 0.0f);
            float inter = iw_ * ih_;
            float uni   = ap + gw*gh - inter;
            float iou   = inter / fmaxf(uni, 1e-6f);
            float dx = pbx - gx, dy = pby - gy;
            float cd2 = dx*dx + dy*dy;
            float ew = fmaxf(fmaxf(pmaxx,gmaxx) - fminf(pminx,gminx), 0.0f);
            float eh = fmaxf(fmaxf(pmaxy,gmaxy) - fminf(pminy,gminy), 0.0f);
            float ed2 = ew*ew + eh*eh;
            float ciou = iou - cd2 / fmaxf(ed2, 1e-6f);
            float dv = atanf(pbw / fmaxf(pbh, 1e-6f)) - atanf(gw / fmaxf(gh, 1e-6f));
            float v = 0.4052847345693511f * dv * dv;     // 4/pi^2
            float alpha = v / fmaxf(1.0f - iou + v, 1e-6f);
            lsum += 1.0f - ciou + alpha * v;

            // class BCE over 80 channels (label smoothing 0.01)
            int ci = scls[tw];
            for (int c = 0; c < NC; ++c) {
                float pc = sigmoid_clip(pin[(size_t)(5+c) * PLANE]);
                float tc = ((c==ci) ? 0.99f : 0.0f) + 0.01f/80.0f;
                lsum += -tc*logf(pc) - (1.0f-tc)*logf(1.0f-pc);
            }
        } else if (!(amax > 0.5f)) {
            // noobj cell: conf BCE target 0 (ignored if anch_iou > 0.5)
            lsum = -logf(1.0f - p);
        }
    }

    red[tid] = lsum;
    __syncthreads();
    #pragma unroll
    for (int s = 128; s > 0; s >>= 1) {
        if (tid < s) red[tid] += red[tid + s];
        __syncthreads();
    }
    if (tid == 0) atomicAdd(out, red[0]);
}

extern "C" void kernel_launch(void* const* d_in, const int* in_sizes, int n_in,
                              void* d_out, int out_size, void* d_ws, size_t ws_size,
                              hipStream_t stream) {
    const float* in  = (const float*)d_in[0];   // (16, 255, 76, 76) f32
    const float* tgt = (const float*)d_in[1];   // (16, 20, 5) f32
    float* out = (float*)d_out;                 // [loss, num_pos]
    float* wsf = (float*)d_ws;

    prep_kernel<<<1, BS*NGT, 0, stream>>>(tgt, wsf, out);

    dim3 grid((CELLS + 255) / 256, BS);
    loss_kernel<<<grid, 256, 0, stream>>>(in, wsf, out);
}

// Round 2
// 24.284 us; speedup vs baseline: 2.3028x; 2.3028x over previous
//
#include <hip/hip_runtime.h>

#define BS   16
#define NGT  20
#define NA   3
#define IH   76
#define IW   76
#define NC   80
#define PLANE (IH*IW)      /* 5776 */
#define CELLS (NA*PLANE)   /* 17328 */
#define NBLK_X 68          /* ceil(CELLS/256) */
#define NPART  (NBLK_X*BS) /* 1088 dense partials */

// ws layout (floats):
//   [0..319]     cx      [320..639]  cy     [640..959]  gw     [960..1279] gh
//   ints at float offset 1280: cell[320] @1280, cls[320] @1600, win[320] @1920
//   partials: dense @2240 (1088), pos @3328 (320)   -> 3648 floats = 14.6 KB
#define WS_INT_OFF   1280
#define WS_DENSE_OFF 2240
#define WS_POS_OFF   (WS_DENSE_OFF + NPART)

__device__ __forceinline__ float softplus_fast(float z) {
    // z pre-clamped to +/-16.118 => exactly matches BCE with 1e-7 clipping
    return fmaxf(z, 0.0f) + __logf(1.0f + __expf(-fabsf(z)));
}

__device__ __forceinline__ float clampz(float z) {
    return fminf(fmaxf(z, -16.118095f), 16.118095f);
}

__global__ void prep_kernel(const float* __restrict__ tgt, float* __restrict__ wsf,
                            float* __restrict__ out)
{
    __shared__ int s_cell[BS*NGT];
    __shared__ int s_cnt;
    int tid = threadIdx.x;            // 0..319 == b*NGT + t
    if (tid == 0) s_cnt = 0;
    int b = tid / NGT;
    int t = tid - b * NGT;

    const float* tp = tgt + (size_t)tid * 5;
    float cx = tp[0] * (float)IW;
    float cy = tp[1] * (float)IH;
    float gw = tp[2] * (float)IW;
    float gh = tp[3] * (float)IH;
    int   cls = (int)tp[4];

    int gi = min(max((int)floorf(cx), 0), IW - 1);
    int gj = min(max((int)floorf(cy), 0), IH - 1);

    const float AW[3] = {1.5f, 2.375f, 5.0f};   // ANCHORS / 8
    const float AH[3] = {2.0f, 4.5f,   3.5f};
    float best_r = -1.0f; int best = 0;
    #pragma unroll
    for (int a = 0; a < NA; ++a) {
        float inter = fminf(gw, AW[a]) * fminf(gh, AH[a]);
        float uni   = gw*gh + AW[a]*AH[a] - inter;
        float r     = inter / uni;
        if (r > best_r) { best_r = r; best = a; }   // first-max wins (jnp.argmax)
    }

    int cell = best * PLANE + gj * IW + gi;
    s_cell[tid] = cell;
    __syncthreads();

    // last-write-wins dedup (matches scatter .set semantics)
    int win = 1;
    for (int t2 = t + 1; t2 < NGT; ++t2)
        if (s_cell[b*NGT + t2] == cell) { win = 0; break; }

    wsf[tid]        = cx;
    wsf[320 + tid]  = cy;
    wsf[640 + tid]  = gw;
    wsf[960 + tid]  = gh;
    int* wi = (int*)(wsf + WS_INT_OFF);
    wi[tid]       = cell;
    wi[320 + tid] = cls;
    wi[640 + tid] = win;

    if (win) atomicAdd(&s_cnt, 1);
    __syncthreads();
    if (tid == 0) out[1] = fmaxf((float)s_cnt, 1.0f);   // num_pos
}

__global__ __launch_bounds__(256) void dense_kernel(const float* __restrict__ in,
                                                    const float* __restrict__ wsf,
                                                    float* __restrict__ partial)
{
    __shared__ float4 sbox[NGT];    // gminx, gmaxx, gminy, gmaxy
    __shared__ float  sarea[NGT];
    __shared__ int    scell[NGT], swin[NGT];
    __shared__ float  red[256];

    int b   = blockIdx.y;
    int tid = threadIdx.x;

    if (tid < NGT) {
        int idx = b*NGT + tid;
        float gx = wsf[idx],      gy = wsf[320 + idx];
        float gw = wsf[640 + idx], gh = wsf[960 + idx];
        sbox[tid]  = make_float4(gx - gw*0.5f, gx + gw*0.5f, gy - gh*0.5f, gy + gh*0.5f);
        sarea[tid] = gw * gh;
        const int* wi = (const int*)(wsf + WS_INT_OFF);
        scell[tid] = wi[idx];
        swin[tid]  = wi[640 + idx];
    }
    __syncthreads();

    int cell = blockIdx.x * 256 + tid;
    float lsum = 0.0f;

    if (cell < CELLS) {
        int a   = cell / PLANE;
        int rem = cell - a * PLANE;
        int j   = rem / IW;
        int i   = rem - j * IW;

        const float* pin = in + ((size_t)b * (NA*(5+NC)) + (size_t)a * (5+NC)) * PLANE + rem;
        float x  = pin[0];
        float y  = pin[PLANE];
        float w  = pin[2*PLANE];
        float h  = pin[3*PLANE];
        float cf = pin[4*PLANE];

        float aw = (a==0) ? 1.5f : ((a==1) ? 2.375f : 5.0f);
        float ah = (a==0) ? 2.0f : ((a==1) ? 4.5f   : 3.5f);

        // reference quirk: pb_x = row_index + x, pb_y = col_index + y, no sigmoid
        float pbx = (float)j + x;
        float pby = (float)i + y;
        float pbw = __expf(w) * aw;
        float pbh = __expf(h) * ah;

        float hw = pbw*0.5f, hh = pbh*0.5f;
        float pminx = pbx-hw, pmaxx = pbx+hw;
        float pminy = pby-hh, pmaxy = pby+hh;
        float ap = pbw * pbh;

        bool ign = false, pos = false;
        #pragma unroll
        for (int t = 0; t < NGT; ++t) {
            float4 gb = sbox[t];
            float iw_ = fmaxf(fminf(pmaxx, gb.y) - fmaxf(pminx, gb.x), 0.0f);
            float ih_ = fmaxf(fminf(pmaxy, gb.w) - fmaxf(pminy, gb.z), 0.0f);
            float inter = iw_ * ih_;
            float uni   = ap + sarea[t] - inter;
            // iou > 0.5  <=>  inter > 0.5*uni   (uni >= gt area > 1 here)
            ign = ign || (inter > 0.5f * uni);
            pos = pos || ((scell[t] == cell) & (swin[t] != 0));
        }

        float z  = clampz(cf);
        float sp = softplus_fast(z);          // = -log(1-sigmoid(z)) = bce(p,0)
        if (pos)       lsum = sp - z;         // bce(p,1) = softplus(z) - z
        else if (!ign) lsum = sp;
    }

    red[tid] = lsum;
    __syncthreads();
    #pragma unroll
    for (int s = 128; s > 0; s >>= 1) {
        if (tid < s) red[tid] += red[tid + s];
        __syncthreads();
    }
    if (tid == 0) partial[blockIdx.y * NBLK_X + blockIdx.x] = red[0];
}

__global__ __launch_bounds__(128) void pos_kernel(const float* __restrict__ in,
                                                  const float* __restrict__ wsf,
                                                  float* __restrict__ partial)
{
    __shared__ int   s_c[NGT], s_k[NGT];
    __shared__ float red[128];

    int idx = blockIdx.x;          // 0..319 == b*NGT + t
    int b   = idx / NGT;
    int tid = threadIdx.x;

    const int* wi = (const int*)(wsf + WS_INT_OFF);
    if (tid < NGT) {
        s_c[tid] = wi[b*NGT + tid];
        s_k[tid] = wi[320 + b*NGT + tid];
    }
    __syncthreads();

    int win  = wi[640 + idx];
    int cell = wi[idx];
    float lsum = 0.0f;

    if (win) {
        int a   = cell / PLANE;
        int rem = cell - a * PLANE;
        const float* pin = in + ((size_t)b * (NA*(5+NC)) + (size_t)a * (5+NC)) * PLANE + rem;

        if (tid < NC) {
            // class BCE: target is multi-hot over ALL gts mapping to this cell
            float tc = 0.01f / (float)NC;                   // label smoothing floor
            #pragma unroll
            for (int t = 0; t < NGT; ++t)
                if (s_c[t] == cell && s_k[t] == tid) tc = 0.99f + 0.01f/(float)NC;
            float z = clampz(pin[(size_t)(5+tid) * PLANE]);
            lsum = softplus_fast(z) - tc * z;               // bce(sigmoid(z), tc)
        } else if (tid == NC) {
            // CIoU vs target box (winner gt)
            int j = rem / IW;
            int i = rem - j * IW;
            float x = pin[0], y = pin[PLANE], w = pin[2*PLANE], h = pin[3*PLANE];
            float aw = (a==0) ? 1.5f : ((a==1) ? 2.375f : 5.0f);
            float ah = (a==0) ? 2.0f : ((a==1) ? 4.5f   : 3.5f);
            float pbx = (float)j + x;
            float pby = (float)i + y;
            float pbw = __expf(w) * aw;
            float pbh = __expf(h) * ah;
            float gx = wsf[idx], gy = wsf[320+idx], gw = wsf[640+idx], gh = wsf[960+idx];

            float hw = pbw*0.5f, hh = pbh*0.5f;
            float pminx = pbx-hw, pmaxx = pbx+hw, pminy = pby-hh, pmaxy = pby+hh;
            float ghw = gw*0.5f, ghh = gh*0.5f;
            float gminx = gx-ghw, gmaxx = gx+ghw, gminy = gy-ghh, gmaxy = gy+ghh;
            float iw_ = fmaxf(fminf(pmaxx,gmaxx) - fmaxf(pminx,gminx), 0.0f);
            float ih_ = fmaxf(fminf(pmaxy,gmaxy) - fmaxf(pminy,gminy), 0.0f);
            float inter = iw_ * ih_;
            float uni   = pbw*pbh + gw*gh - inter;
            float iou   = inter / fmaxf(uni, 1e-6f);
            float dx = pbx - gx, dy = pby - gy;
            float cd2 = dx*dx + dy*dy;
            float ew = fmaxf(fmaxf(pmaxx,gmaxx) - fminf(pminx,gminx), 0.0f);
            float eh = fmaxf(fmaxf(pmaxy,gmaxy) - fminf(pminy,gminy), 0.0f);
            float ed2 = ew*ew + eh*eh;
            float ciou = iou - cd2 / fmaxf(ed2, 1e-6f);
            float dv = atanf(pbw / fmaxf(pbh, 1e-6f)) - atanf(gw / fmaxf(gh, 1e-6f));
            float v = 0.4052847345693511f * dv * dv;        // 4/pi^2
            float alpha = v / fmaxf(1.0f - iou + v, 1e-6f);
            lsum = 1.0f - ciou + alpha * v;
        }
    }

    red[tid] = lsum;
    __syncthreads();
    #pragma unroll
    for (int s = 64; s > 0; s >>= 1) {
        if (tid < s) red[tid] += red[tid + s];
        __syncthreads();
    }
    if (tid == 0) partial[idx] = red[0];
}

__global__ __launch_bounds__(256) void finalize_kernel(const float* __restrict__ partial,
                                                       float* __restrict__ out)
{
    __shared__ float red[256];
    int tid = threadIdx.x;
    float s = 0.0f;
    for (int k = tid; k < NPART + BS*NGT; k += 256) s += partial[k];
    red[tid] = s;
    __syncthreads();
    #pragma unroll
    for (int st = 128; st > 0; st >>= 1) {
        if (tid < st) red[tid] += red[tid + st];
        __syncthreads();
    }
    if (tid == 0) out[0] = red[0];
}

extern "C" void kernel_launch(void* const* d_in, const int* in_sizes, int n_in,
                              void* d_out, int out_size, void* d_ws, size_t ws_size,
                              hipStream_t stream) {
    const float* in  = (const float*)d_in[0];   // (16, 255, 76, 76) f32
    const float* tgt = (const float*)d_in[1];   // (16, 20, 5) f32
    float* out = (float*)d_out;                 // [loss, num_pos]
    float* wsf = (float*)d_ws;

    prep_kernel<<<1, BS*NGT, 0, stream>>>(tgt, wsf, out);

    dim3 grid(NBLK_X, BS);
    dense_kernel<<<grid, 256, 0, stream>>>(in, wsf, wsf + WS_DENSE_OFF);

    pos_kernel<<<BS*NGT, 128, 0, stream>>>(in, wsf, wsf + WS_POS_OFF);

    finalize_kernel<<<1, 256, 0, stream>>>(wsf + WS_DENSE_OFF, out);
}

// Round 3
// 19.678 us; speedup vs baseline: 2.8418x; 1.2341x over previous
//
#include <hip/hip_runtime.h>

#define BS   16
#define NGT  20
#define NA   3
#define IH   76
#define IW   76
#define NC   80
#define PLANE (IH*IW)      /* 5776 */
#define CELLS (NA*PLANE)   /* 17328 */
#define NBLK_X 68          /* ceil(CELLS/256) dense blocks per batch */
#define NPART  (NBLK_X*BS) /* 1088 dense partials */
#define NPOS   (NGT*BS)    /* 320 pos partials */
// ws floats: dense partials [0,1088) | pos partials [1088,1408) | wincnt [1408,1424)
#define WS_POS_OFF 1088
#define WS_CNT_OFF 1408

__device__ __forceinline__ float softplus_fast(float z) {
    // z pre-clamped to +/-16.118 => exactly matches BCE with 1e-7 clipping
    return fmaxf(z, 0.0f) + __logf(1.0f + __expf(-fabsf(z)));
}
__device__ __forceinline__ float clampz(float z) {
    return fminf(fmaxf(z, -16.118095f), 16.118095f);
}

__global__ __launch_bounds__(256) void main_kernel(const float* __restrict__ in,
                                                   const float* __restrict__ tgt,
                                                   float* __restrict__ ws)
{
    __shared__ float4 sbox[NGT];    // gminx, gmaxx, gminy, gmaxy
    __shared__ float4 sg[NGT];      // gx, gy, gw, gh
    __shared__ float  sarea[NGT];
    __shared__ int    scell[NGT], swin[NGT], scls[NGT];
    __shared__ float  red[256];

    int b   = blockIdx.y;
    int tid = threadIdx.x;

    // --- per-block prep: recompute this batch's 20 GT assignments (tiny) ---
    if (tid < NGT) {
        const float* tp = tgt + ((size_t)(b*NGT + tid)) * 5;
        float cx = tp[0] * (float)IW;
        float cy = tp[1] * (float)IH;
        float gw = tp[2] * (float)IW;
        float gh = tp[3] * (float)IH;
        int   cls = (int)tp[4];

        int gi = min(max((int)floorf(cx), 0), IW - 1);
        int gj = min(max((int)floorf(cy), 0), IH - 1);

        const float AW[3] = {1.5f, 2.375f, 5.0f};   // ANCHORS / stride(8)
        const float AH[3] = {2.0f, 4.5f,   3.5f};
        float best_r = -1.0f; int best = 0;
        #pragma unroll
        for (int a = 0; a < NA; ++a) {
            float inter = fminf(gw, AW[a]) * fminf(gh, AH[a]);
            float uni   = gw*gh + AW[a]*AH[a] - inter;
            float r     = inter / uni;
            if (r > best_r) { best_r = r; best = a; }   // first-max wins (jnp.argmax)
        }

        scell[tid] = best * PLANE + gj * IW + gi;
        scls[tid]  = cls;
        sg[tid]    = make_float4(cx, cy, gw, gh);
        sbox[tid]  = make_float4(cx - gw*0.5f, cx + gw*0.5f, cy - gh*0.5f, cy + gh*0.5f);
        sarea[tid] = gw * gh;
    }
    __syncthreads();
    if (tid < NGT) {
        // last-write-wins dedup (matches scatter .set semantics)
        int win = 1, mycell = scell[tid];
        for (int t2 = tid + 1; t2 < NGT; ++t2)
            if (scell[t2] == mycell) { win = 0; break; }
        swin[tid] = win;
    }
    __syncthreads();

    float lsum = 0.0f;
    int outIdx;

    if (blockIdx.x < NBLK_X) {
        // ---------------- dense path: conf BCE with ignore mask ----------------
        outIdx = b * NBLK_X + blockIdx.x;
        int cell = blockIdx.x * 256 + tid;
        if (cell < CELLS) {
            int a   = cell / PLANE;
            int rem = cell - a * PLANE;
            int j   = rem / IW;
            int i   = rem - j * IW;

            const float* pin = in + ((size_t)b * (NA*(5+NC)) + (size_t)a * (5+NC)) * PLANE + rem;
            float x  = pin[0];
            float y  = pin[PLANE];
            float w  = pin[2*PLANE];
            float h  = pin[3*PLANE];
            float cf = pin[4*PLANE];

            float aw = (a==0) ? 1.5f : ((a==1) ? 2.375f : 5.0f);
            float ah = (a==0) ? 2.0f : ((a==1) ? 4.5f   : 3.5f);

            // reference quirk: pb_x = row_index + x, pb_y = col_index + y, no sigmoid
            float pbx = (float)j + x;
            float pby = (float)i + y;
            float pbw = __expf(w) * aw;
            float pbh = __expf(h) * ah;

            float hw = pbw*0.5f, hh = pbh*0.5f;
            float pminx = pbx-hw, pmaxx = pbx+hw;
            float pminy = pby-hh, pmaxy = pby+hh;
            float ap = pbw * pbh;

            bool ign = false, pos = false;
            #pragma unroll
            for (int t = 0; t < NGT; ++t) {
                float4 gb = sbox[t];
                float iw_ = fmaxf(fminf(pmaxx, gb.y) - fmaxf(pminx, gb.x), 0.0f);
                float ih_ = fmaxf(fminf(pmaxy, gb.w) - fmaxf(pminy, gb.z), 0.0f);
                float inter = iw_ * ih_;
                float uni   = ap + sarea[t] - inter;
                // iou > 0.5  <=>  inter > 0.5*uni  (uni >= gt_area > 1 here)
                ign = ign || (inter > 0.5f * uni);
                pos = pos || ((scell[t] == cell) & (swin[t] != 0));
            }

            float z  = clampz(cf);
            float sp = softplus_fast(z);        // bce(sigmoid(z), 0)
            if (pos)       lsum = sp - z;       // bce(sigmoid(z), 1)
            else if (!ign) lsum = sp;
        }
    } else {
        // ---------------- pos path: class BCE + CIoU for one GT ----------------
        int t = blockIdx.x - NBLK_X;
        outIdx = WS_POS_OFF + b * NGT + t;
        int win  = swin[t];
        int cell = scell[t];

        if (t == 0 && tid == 0) {
            int cnt = 0;
            #pragma unroll
            for (int u = 0; u < NGT; ++u) cnt += swin[u];
            ws[WS_CNT_OFF + b] = (float)cnt;
        }

        if (win) {
            int a   = cell / PLANE;
            int rem = cell - a * PLANE;
            const float* pin = in + ((size_t)b * (NA*(5+NC)) + (size_t)a * (5+NC)) * PLANE + rem;

            if (tid < NC) {
                // class BCE: target multi-hot over ALL gts mapping to this cell
                float tc = 0.01f / (float)NC;
                #pragma unroll
                for (int u = 0; u < NGT; ++u)
                    if (scell[u] == cell && scls[u] == tid) tc = 0.99f + 0.01f/(float)NC;
                float z = clampz(pin[(size_t)(5+tid) * PLANE]);
                lsum = softplus_fast(z) - tc * z;
            } else if (tid == NC) {
                // CIoU vs this gt's box
                int j = rem / IW;
                int i = rem - j * IW;
                float x = pin[0], y = pin[PLANE], w = pin[2*PLANE], h = pin[3*PLANE];
                float aw = (a==0) ? 1.5f : ((a==1) ? 2.375f : 5.0f);
                float ah = (a==0) ? 2.0f : ((a==1) ? 4.5f   : 3.5f);
                float pbx = (float)j + x;
                float pby = (float)i + y;
                float pbw = __expf(w) * aw;
                float pbh = __expf(h) * ah;
                float4 g = sg[t];
                float gx = g.x, gy = g.y, gw = g.z, gh = g.w;

                float hw = pbw*0.5f, hh = pbh*0.5f;
                float pminx = pbx-hw, pmaxx = pbx+hw, pminy = pby-hh, pmaxy = pby+hh;
                float ghw = gw*0.5f, ghh = gh*0.5f;
                float gminx = gx-ghw, gmaxx = gx+ghw, gminy = gy-ghh, gmaxy = gy+ghh;
                float iw_ = fmaxf(fminf(pmaxx,gmaxx) - fmaxf(pminx,gminx), 0.0f);
                float ih_ = fmaxf(fminf(pmaxy,gmaxy) - fmaxf(pminy,gminy), 0.0f);
                float inter = iw_ * ih_;
                float uni   = pbw*pbh + gw*gh - inter;
                float iou   = inter / fmaxf(uni, 1e-6f);
                float dx = pbx - gx, dy = pby - gy;
                float cd2 = dx*dx + dy*dy;
                float ew = fmaxf(fmaxf(pmaxx,gmaxx) - fminf(pminx,gminx), 0.0f);
                float eh = fmaxf(fmaxf(pmaxy,gmaxy) - fminf(pminy,gminy), 0.0f);
                float ed2 = ew*ew + eh*eh;
                float ciou = iou - cd2 / fmaxf(ed2, 1e-6f);
                float dv = atanf(pbw / fmaxf(pbh, 1e-6f)) - atanf(gw / fmaxf(gh, 1e-6f));
                float v = 0.4052847345693511f * dv * dv;   // 4/pi^2
                float alpha = v / fmaxf(1.0f - iou + v, 1e-6f);
                lsum = 1.0f - ciou + alpha * v;
            }
        }
    }

    red[tid] = lsum;
    __syncthreads();
    #pragma unroll
    for (int s = 128; s > 0; s >>= 1) {
        if (tid < s) red[tid] += red[tid + s];
        __syncthreads();
    }
    if (tid == 0) ws[outIdx] = red[0];
}

__global__ __launch_bounds__(256) void finalize_kernel(const float* __restrict__ ws,
                                                       float* __restrict__ out)
{
    __shared__ float red[256];
    int tid = threadIdx.x;
    float s = 0.0f;
    for (int k = tid; k < NPART + NPOS; k += 256) s += ws[k];
    red[tid] = s;
    __syncthreads();
    #pragma unroll
    for (int st = 128; st > 0; st >>= 1) {
        if (tid < st) red[tid] += red[tid + st];
        __syncthreads();
    }
    if (tid == 0) {
        out[0] = red[0];
        float np = 0.0f;
        #pragma unroll
        for (int b = 0; b < BS; ++b) np += ws[WS_CNT_OFF + b];
        out[1] = fmaxf(np, 1.0f);
    }
}

extern "C" void kernel_launch(void* const* d_in, const int* in_sizes, int n_in,
                              void* d_out, int out_size, void* d_ws, size_t ws_size,
                              hipStream_t stream) {
    const float* in  = (const float*)d_in[0];   // (16, 255, 76, 76) f32
    const float* tgt = (const float*)d_in[1];   // (16, 20, 5) f32
    float* out = (float*)d_out;                 // [loss, num_pos]
    float* ws  = (float*)d_ws;

    dim3 grid(NBLK_X + NGT, BS);                // 68 dense + 20 pos blocks per batch
    main_kernel<<<grid, 256, 0, stream>>>(in, tgt, ws);
    finalize_kernel<<<1, 256, 0, stream>>>(ws, out);
}